// Round 2
// baseline (176.437 us; speedup 1.0000x reference)
//
#include <hip/hip_runtime.h>

#define SQ_ 512      // queries
#define MQ_ 256      // candidates per query
#define SM_ (SQ_ * MQ_)
#define DQ_ 1024     // embedding dim
#define KQ_ 5
#define EPSQ 1e-8f
#define NB_ 1024     // coarse buckets (idx>>7, idx<100000 -> bucket<782)

// ---------------- sort machinery: bucket by idx>>7 ----------------
__global__ void zero_hist_kernel(int* __restrict__ hist) {
    int i = blockIdx.x * blockDim.x + threadIdx.x;
    if (i < NB_) hist[i] = 0;
}

__global__ void hist_kernel(const int* __restrict__ bidx, int* __restrict__ hist) {
    int i = blockIdx.x * blockDim.x + threadIdx.x;
    if (i < SM_) atomicAdd(&hist[bidx[i] >> 7], 1);
}

__global__ void scan_kernel(const int* __restrict__ hist, int* __restrict__ cursor) {
    __shared__ int tmp[NB_];
    int tid = threadIdx.x;
    tmp[tid] = hist[tid];
    __syncthreads();
    for (int off = 1; off < NB_; off <<= 1) {
        int v = (tid >= off) ? tmp[tid - off] : 0;
        __syncthreads();
        tmp[tid] += v;
        __syncthreads();
    }
    cursor[tid] = (tid == 0) ? 0 : tmp[tid - 1];   // exclusive scan
}

__global__ void scatter_kernel(const int* __restrict__ bidx, int* __restrict__ cursor,
                               int* __restrict__ sidx, int* __restrict__ ssm) {
    int i = blockIdx.x * blockDim.x + threadIdx.x;
    if (i >= SM_) return;
    int idx = bidx[i];
    int pos = atomicAdd(&cursor[idx >> 7], 1);
    sidx[pos] = idx;   // bank row
    ssm[pos] = i;      // flat (s,m): s = i>>8, m = i&255
}

// ---------------- kernel: query norms ----------------
__global__ void qnorm_kernel(const float* __restrict__ q, float* __restrict__ qn) {
    int wave = (int)((blockIdx.x * blockDim.x + threadIdx.x) >> 6);
    int lane = threadIdx.x & 63;
    if (wave >= SQ_) return;
    const float4* row = (const float4*)(q + (size_t)wave * DQ_);
    float sq = 0.f;
#pragma unroll
    for (int i = 0; i < DQ_ / 4 / 64; ++i) {
        float4 v = row[lane + i * 64];
        sq += v.x * v.x + v.y * v.y + v.z * v.z + v.w * v.w;
    }
#pragma unroll
    for (int off = 32; off; off >>= 1) sq += __shfl_xor(sq, off);
    if (lane == 0) qn[wave] = fmaxf(sqrtf(sq), EPSQ);
}

// ---------------- kernel: cosine sims in bucket-sorted order ----------------
__global__ void sim_kernel(const float* __restrict__ q,
                           const float* __restrict__ bank,
                           const float* __restrict__ labels,
                           const int* __restrict__ sidx,
                           const int* __restrict__ ssm,
                           const float* __restrict__ qn,
                           float* __restrict__ sims,
                           float* __restrict__ slab) {
    long long gw = (long long)(blockIdx.x * (long long)blockDim.x + threadIdx.x) >> 6;
    int lane = threadIdx.x & 63;
    if (gw >= (long long)SM_) return;
    int idx = sidx[gw];
    int sm  = ssm[gw];
    int s = sm >> 8;
    const float4* crow = (const float4*)(bank + (long long)idx * DQ_);
    const float4* qrow = (const float4*)(q + (size_t)s * DQ_);
    float dot = 0.f, sq = 0.f;
#pragma unroll
    for (int i = 0; i < 4; ++i) {
        int j = lane + i * 64;
        float4 c = crow[j];
        float4 qq = qrow[j];
        dot += c.x * qq.x + c.y * qq.y + c.z * qq.z + c.w * qq.w;
        sq  += c.x * c.x + c.y * c.y + c.z * c.z + c.w * c.w;
    }
#pragma unroll
    for (int off = 32; off; off >>= 1) {
        dot += __shfl_xor(dot, off);
        sq  += __shfl_xor(sq, off);
    }
    if (lane == 0) {
        float cn = fmaxf(sqrtf(sq), EPSQ);
        sims[sm] = dot / (qn[s] * cn);
        slab[sm] = labels[idx];
    }
}

// ---------------- kernel: top-5 + mean + round ----------------
__global__ void topk_kernel(const float* __restrict__ sims,
                            const float* __restrict__ slab,
                            float* __restrict__ out) {
    int gw = (int)((blockIdx.x * blockDim.x + threadIdx.x) >> 6);
    int lane = threadIdx.x & 63;
    if (gw >= SQ_) return;
    const float* srow = sims + (size_t)gw * MQ_;
    const float* lrow = slab + (size_t)gw * MQ_;
    float v[4];
#pragma unroll
    for (int i = 0; i < 4; ++i) v[i] = srow[lane + i * 64];
    float sum = 0.f;
    for (int t = 0; t < KQ_; ++t) {
        float bv = v[0];
        int bi = lane;
#pragma unroll
        for (int i = 1; i < 4; ++i) {
            if (v[i] > bv) { bv = v[i]; bi = lane + i * 64; }
        }
#pragma unroll
        for (int off = 32; off; off >>= 1) {
            float ov = __shfl_xor(bv, off);
            int oi = __shfl_xor(bi, off);
            if (ov > bv || (ov == bv && oi < bi)) { bv = ov; bi = oi; }
        }
        sum += lrow[bi];
        if ((bi & 63) == lane) v[bi >> 6] = -2.0f;   // sims in [-1,1]
    }
    if (lane == 0) out[gw] = rintf(sum / (float)KQ_);
}

extern "C" void kernel_launch(void* const* d_in, const int* in_sizes, int n_in,
                              void* d_out, int out_size, void* d_ws, size_t ws_size,
                              hipStream_t stream) {
    const float* q      = (const float*)d_in[0];   // [S, D]
    const float* bank   = (const float*)d_in[1];   // [N, D]
    const float* labels = (const float*)d_in[2];   // [N]
    const int*   bidx   = (const int*)d_in[3];     // [S, M]

    float* out = (float*)d_out;                    // [S]

    // workspace layout (floats/ints, all 4B)
    float* sims   = (float*)d_ws;                  // SM floats
    float* slab   = sims + SM_;                    // SM floats
    float* qn     = slab + SM_;                    // SQ floats
    int*   hist   = (int*)(qn + SQ_);              // NB ints
    int*   cursor = hist + NB_;                    // NB ints
    int*   sidx   = cursor + NB_;                  // SM ints
    int*   ssm    = sidx + SM_;                    // SM ints

    zero_hist_kernel<<<(NB_ + 255) / 256, 256, 0, stream>>>(hist);
    hist_kernel<<<(SM_ + 255) / 256, 256, 0, stream>>>(bidx, hist);
    scan_kernel<<<1, NB_, 0, stream>>>(hist, cursor);
    scatter_kernel<<<(SM_ + 255) / 256, 256, 0, stream>>>(bidx, cursor, sidx, ssm);

    qnorm_kernel<<<SQ_ / 4, 256, 0, stream>>>(q, qn);

    sim_kernel<<<SM_ / 4, 256, 0, stream>>>(q, bank, labels, sidx, ssm, qn, sims, slab);

    topk_kernel<<<SQ_ / 4, 256, 0, stream>>>(sims, slab, out);
}

// Round 3
// 113.557 us; speedup vs baseline: 1.5537x; 1.5537x over previous
//
#include <hip/hip_runtime.h>

#define SQ_ 512        // queries
#define MQ_ 256        // candidates per query
#define SM_ (SQ_ * MQ_)
#define DQ_ 1024       // embedding dim
#define KQ_ 5
#define EPSQ 1e-8f
#define NROW_ 100000   // bank rows
#define NPAD_ 100352   // 98 * 1024
#define NBLK_ 98       // scan blocks of 1024

// ---------------- zero hist (padded) ----------------
__global__ void zero_kernel(int* __restrict__ hist) {
    int i = blockIdx.x * blockDim.x + threadIdx.x;
    if (i < NPAD_) hist[i] = 0;
}

// ---------------- histogram over exact idx ----------------
__global__ void hist_kernel(const int* __restrict__ bidx, int* __restrict__ hist) {
    int i = blockIdx.x * blockDim.x + threadIdx.x;
    if (i < SM_) atomicAdd(&hist[bidx[i]], 1);
}

// ---------------- hierarchical exclusive scan: A (per-block) ----------------
__global__ void scanA_kernel(const int* __restrict__ hist, int* __restrict__ gstart,
                             int* __restrict__ blocksum) {
    __shared__ int tmp[1024];
    int t = threadIdx.x;
    int i = blockIdx.x * 1024 + t;
    int v = hist[i];
    tmp[t] = v;
    __syncthreads();
    for (int off = 1; off < 1024; off <<= 1) {
        int u = (t >= off) ? tmp[t - off] : 0;
        __syncthreads();
        tmp[t] += u;
        __syncthreads();
    }
    gstart[i] = tmp[t] - v;                 // exclusive within block
    if (t == 1023) blocksum[blockIdx.x] = tmp[t];
}

// ---------------- scan B (block sums, 98 <= 128) ----------------
__global__ void scanB_kernel(int* __restrict__ blocksum, int* __restrict__ blockoff) {
    __shared__ int tmp[128];
    int t = threadIdx.x;
    int v = (t < NBLK_) ? blocksum[t] : 0;
    tmp[t] = v;
    __syncthreads();
    for (int off = 1; off < 128; off <<= 1) {
        int u = (t >= off) ? tmp[t - off] : 0;
        __syncthreads();
        tmp[t] += u;
        __syncthreads();
    }
    blockoff[t] = tmp[t] - v;               // exclusive
}

// ---------------- scan C (add offsets, init cursor) ----------------
__global__ void scanC_kernel(int* __restrict__ gstart, const int* __restrict__ blockoff,
                             int* __restrict__ cursor) {
    int i = blockIdx.x * blockDim.x + threadIdx.x;
    if (i >= NPAD_) return;
    int g = gstart[i] + blockoff[i >> 10];
    gstart[i] = g;
    cursor[i] = g;
}

// ---------------- scatter (s,m) items into idx-grouped order ----------------
__global__ void scatter_kernel(const int* __restrict__ bidx, int* __restrict__ cursor,
                               int* __restrict__ ssm) {
    int i = blockIdx.x * blockDim.x + threadIdx.x;
    if (i >= SM_) return;
    int idx = bidx[i];
    int pos = atomicAdd(&cursor[idx], 1);
    ssm[pos] = i;                           // flat (s,m): s = i>>8
}

// ---------------- query norms ----------------
__global__ void qnorm_kernel(const float* __restrict__ q, float* __restrict__ qn) {
    int wave = (int)((blockIdx.x * blockDim.x + threadIdx.x) >> 6);
    int lane = threadIdx.x & 63;
    if (wave >= SQ_) return;
    const float4* row = (const float4*)(q + (size_t)wave * DQ_);
    float sq = 0.f;
#pragma unroll
    for (int i = 0; i < 4; ++i) {
        float4 v = row[lane + i * 64];
        sq += v.x * v.x + v.y * v.y + v.z * v.z + v.w * v.w;
    }
#pragma unroll
    for (int off = 32; off; off >>= 1) sq += __shfl_xor(sq, off);
    if (lane == 0) qn[wave] = fmaxf(sqrtf(sq), EPSQ);
}

// ---------------- grouped sims: one wave per unique bank row ----------------
__global__ void simg_kernel(const float* __restrict__ q,
                            const float* __restrict__ bank,
                            const float* __restrict__ labels,
                            const int* __restrict__ hist,
                            const int* __restrict__ gstart,
                            const int* __restrict__ ssm,
                            const float* __restrict__ qn,
                            float* __restrict__ sims,
                            float* __restrict__ slab) {
    int row = (int)((blockIdx.x * (long long)blockDim.x + threadIdx.x) >> 6);
    int lane = threadIdx.x & 63;
    if (row >= NROW_) return;
    int count = hist[row];
    if (count == 0) return;
    int start = gstart[row];

    // read the bank row ONCE into registers (64 B / lane)
    const float4* crow = (const float4*)(bank + (long long)row * DQ_);
    float4 c0 = crow[lane];
    float4 c1 = crow[lane + 64];
    float4 c2 = crow[lane + 128];
    float4 c3 = crow[lane + 192];

    float sq = c0.x * c0.x + c0.y * c0.y + c0.z * c0.z + c0.w * c0.w
             + c1.x * c1.x + c1.y * c1.y + c1.z * c1.z + c1.w * c1.w
             + c2.x * c2.x + c2.y * c2.y + c2.z * c2.z + c2.w * c2.w
             + c3.x * c3.x + c3.y * c3.y + c3.z * c3.z + c3.w * c3.w;
#pragma unroll
    for (int off = 32; off; off >>= 1) sq += __shfl_xor(sq, off);
    float cn = fmaxf(sqrtf(sq), EPSQ);
    float lab = labels[row];

    for (int j = 0; j < count; ++j) {
        int sm = ssm[start + j];
        int s = sm >> 8;
        const float4* qrow = (const float4*)(q + (size_t)s * DQ_);
        float4 q0 = qrow[lane];
        float4 q1 = qrow[lane + 64];
        float4 q2 = qrow[lane + 128];
        float4 q3 = qrow[lane + 192];
        // same per-lane accumulation order as R1 (i = 0..3) -> bitwise-identical sims
        float dot = 0.f;
        dot += c0.x * q0.x + c0.y * q0.y + c0.z * q0.z + c0.w * q0.w;
        dot += c1.x * q1.x + c1.y * q1.y + c1.z * q1.z + c1.w * q1.w;
        dot += c2.x * q2.x + c2.y * q2.y + c2.z * q2.z + c2.w * q2.w;
        dot += c3.x * q3.x + c3.y * q3.y + c3.z * q3.z + c3.w * q3.w;
#pragma unroll
        for (int off = 32; off; off >>= 1) dot += __shfl_xor(dot, off);
        if (lane == 0) {
            sims[sm] = dot / (qn[s] * cn);
            slab[sm] = lab;
        }
    }
}

// ---------------- top-5 + mean + round ----------------
__global__ void topk_kernel(const float* __restrict__ sims,
                            const float* __restrict__ slab,
                            float* __restrict__ out) {
    int gw = (int)((blockIdx.x * blockDim.x + threadIdx.x) >> 6);
    int lane = threadIdx.x & 63;
    if (gw >= SQ_) return;
    const float* srow = sims + (size_t)gw * MQ_;
    const float* lrow = slab + (size_t)gw * MQ_;
    float v[4];
#pragma unroll
    for (int i = 0; i < 4; ++i) v[i] = srow[lane + i * 64];
    float sum = 0.f;
    for (int t = 0; t < KQ_; ++t) {
        float bv = v[0];
        int bi = lane;
#pragma unroll
        for (int i = 1; i < 4; ++i) {
            if (v[i] > bv) { bv = v[i]; bi = lane + i * 64; }
        }
#pragma unroll
        for (int off = 32; off; off >>= 1) {
            float ov = __shfl_xor(bv, off);
            int oi = __shfl_xor(bi, off);
            if (ov > bv || (ov == bv && oi < bi)) { bv = ov; bi = oi; }
        }
        sum += lrow[bi];
        if ((bi & 63) == lane) v[bi >> 6] = -2.0f;   // sims in [-1,1]
    }
    if (lane == 0) out[gw] = rintf(sum / (float)KQ_);
}

extern "C" void kernel_launch(void* const* d_in, const int* in_sizes, int n_in,
                              void* d_out, int out_size, void* d_ws, size_t ws_size,
                              hipStream_t stream) {
    const float* q      = (const float*)d_in[0];   // [S, D]
    const float* bank   = (const float*)d_in[1];   // [N, D]
    const float* labels = (const float*)d_in[2];   // [N]
    const int*   bidx   = (const int*)d_in[3];     // [S, M]

    float* out = (float*)d_out;                    // [S]

    // workspace layout (all 4 B elements)
    float* sims     = (float*)d_ws;                // SM
    float* slab     = sims + SM_;                  // SM
    float* qn       = slab + SM_;                  // SQ
    int*   hist     = (int*)(qn + SQ_);            // NPAD
    int*   gstart   = hist + NPAD_;                // NPAD
    int*   cursor   = gstart + NPAD_;              // NPAD
    int*   blocksum = cursor + NPAD_;              // 128
    int*   blockoff = blocksum + 128;              // 128
    int*   ssm      = blockoff + 128;              // SM

    zero_kernel<<<(NPAD_ + 255) / 256, 256, 0, stream>>>(hist);
    hist_kernel<<<(SM_ + 255) / 256, 256, 0, stream>>>(bidx, hist);
    scanA_kernel<<<NBLK_, 1024, 0, stream>>>(hist, gstart, blocksum);
    scanB_kernel<<<1, 128, 0, stream>>>(blocksum, blockoff);
    scanC_kernel<<<(NPAD_ + 255) / 256, 256, 0, stream>>>(gstart, blockoff, cursor);
    scatter_kernel<<<(SM_ + 255) / 256, 256, 0, stream>>>(bidx, cursor, ssm);

    qnorm_kernel<<<SQ_ / 4, 256, 0, stream>>>(q, qn);

    // one wave per bank row: 100000 waves, 4 waves/block
    simg_kernel<<<(NROW_ + 3) / 4, 256, 0, stream>>>(q, bank, labels, hist, gstart, ssm,
                                                     qn, sims, slab);

    topk_kernel<<<SQ_ / 4, 256, 0, stream>>>(sims, slab, out);
}

// Round 4
// 113.419 us; speedup vs baseline: 1.5556x; 1.0012x over previous
//
#include <hip/hip_runtime.h>

#define SQ_ 512        // queries
#define MQ_ 256        // candidates per query
#define SM_ (SQ_ * MQ_)
#define DQ_ 1024       // embedding dim
#define KQ_ 5
#define EPSQ 1e-8f
#define NROW_ 100000   // bank rows
#define NPAD_ 100352   // 98 * 1024
#define NBLK_ 98       // scan blocks of 1024

typedef float f4 __attribute__((ext_vector_type(4)));

// ---------------- zero hist (padded) ----------------
__global__ void zero_kernel(int* __restrict__ hist) {
    int i = blockIdx.x * blockDim.x + threadIdx.x;
    if (i < NPAD_) hist[i] = 0;
}

// ---------------- histogram over exact idx ----------------
__global__ void hist_kernel(const int* __restrict__ bidx, int* __restrict__ hist) {
    int i = blockIdx.x * blockDim.x + threadIdx.x;
    if (i < SM_) atomicAdd(&hist[bidx[i]], 1);
}

// ---------------- hierarchical exclusive scan: A (per-block) ----------------
__global__ void scanA_kernel(const int* __restrict__ hist, int* __restrict__ gstart,
                             int* __restrict__ blocksum) {
    __shared__ int tmp[1024];
    int t = threadIdx.x;
    int i = blockIdx.x * 1024 + t;
    int v = hist[i];
    tmp[t] = v;
    __syncthreads();
    for (int off = 1; off < 1024; off <<= 1) {
        int u = (t >= off) ? tmp[t - off] : 0;
        __syncthreads();
        tmp[t] += u;
        __syncthreads();
    }
    gstart[i] = tmp[t] - v;                 // exclusive within block
    if (t == 1023) blocksum[blockIdx.x] = tmp[t];
}

// ---------------- scan B (block sums, 98 <= 128) ----------------
__global__ void scanB_kernel(int* __restrict__ blocksum, int* __restrict__ blockoff) {
    __shared__ int tmp[128];
    int t = threadIdx.x;
    int v = (t < NBLK_) ? blocksum[t] : 0;
    tmp[t] = v;
    __syncthreads();
    for (int off = 1; off < 128; off <<= 1) {
        int u = (t >= off) ? tmp[t - off] : 0;
        __syncthreads();
        tmp[t] += u;
        __syncthreads();
    }
    blockoff[t] = tmp[t] - v;               // exclusive
}

// ---------------- scan C (add offsets, init cursor) ----------------
__global__ void scanC_kernel(int* __restrict__ gstart, const int* __restrict__ blockoff,
                             int* __restrict__ cursor) {
    int i = blockIdx.x * blockDim.x + threadIdx.x;
    if (i >= NPAD_) return;
    int g = gstart[i] + blockoff[i >> 10];
    gstart[i] = g;
    cursor[i] = g;
}

// ---------------- scatter (s,m) items into idx-grouped order ----------------
__global__ void scatter_kernel(const int* __restrict__ bidx, int* __restrict__ cursor,
                               int* __restrict__ ssm) {
    int i = blockIdx.x * blockDim.x + threadIdx.x;
    if (i >= SM_) return;
    int idx = bidx[i];
    int pos = atomicAdd(&cursor[idx], 1);
    ssm[pos] = i;                           // flat (s,m): s = i>>8
}

// ---------------- query norms ----------------
__global__ void qnorm_kernel(const float* __restrict__ q, float* __restrict__ qn) {
    int wave = (int)((blockIdx.x * blockDim.x + threadIdx.x) >> 6);
    int lane = threadIdx.x & 63;
    if (wave >= SQ_) return;
    const float4* row = (const float4*)(q + (size_t)wave * DQ_);
    float sq = 0.f;
#pragma unroll
    for (int i = 0; i < 4; ++i) {
        float4 v = row[lane + i * 64];
        sq += v.x * v.x + v.y * v.y + v.z * v.z + v.w * v.w;
    }
#pragma unroll
    for (int off = 32; off; off >>= 1) sq += __shfl_xor(sq, off);
    if (lane == 0) qn[wave] = fmaxf(sqrtf(sq), EPSQ);
}

// ---------------- grouped sims: one wave per unique bank row ----------------
// Bank rows are single-use (after dedup): load NON-TEMPORAL so the 300 MB
// stream doesn't evict the 2 MB of query rows from L2/L3.
__global__ void simg_kernel(const float* __restrict__ q,
                            const float* __restrict__ bank,
                            const float* __restrict__ labels,
                            const int* __restrict__ hist,
                            const int* __restrict__ gstart,
                            const int* __restrict__ ssm,
                            const float* __restrict__ qn,
                            float* __restrict__ sims,
                            float* __restrict__ slab) {
    int row = (int)((blockIdx.x * (long long)blockDim.x + threadIdx.x) >> 6);
    int lane = threadIdx.x & 63;
    if (row >= NROW_) return;
    int count = hist[row];
    if (count == 0) return;
    int start = gstart[row];

    const f4* crow = (const f4*)(bank + (long long)row * DQ_);
    f4 c0 = __builtin_nontemporal_load(crow + lane);
    f4 c1 = __builtin_nontemporal_load(crow + lane + 64);
    f4 c2 = __builtin_nontemporal_load(crow + lane + 128);
    f4 c3 = __builtin_nontemporal_load(crow + lane + 192);

    float sq = c0.x * c0.x + c0.y * c0.y + c0.z * c0.z + c0.w * c0.w
             + c1.x * c1.x + c1.y * c1.y + c1.z * c1.z + c1.w * c1.w
             + c2.x * c2.x + c2.y * c2.y + c2.z * c2.z + c2.w * c2.w
             + c3.x * c3.x + c3.y * c3.y + c3.z * c3.z + c3.w * c3.w;
#pragma unroll
    for (int off = 32; off; off >>= 1) sq += __shfl_xor(sq, off);
    float cn = fmaxf(sqrtf(sq), EPSQ);
    float lab = labels[row];

    for (int j = 0; j < count; ++j) {
        int sm = ssm[start + j];
        int s = sm >> 8;
        const float4* qrow = (const float4*)(q + (size_t)s * DQ_);
        float4 q0 = qrow[lane];
        float4 q1 = qrow[lane + 64];
        float4 q2 = qrow[lane + 128];
        float4 q3 = qrow[lane + 192];
        // same per-lane accumulation order as R1 -> bitwise-identical sims
        float dot = 0.f;
        dot += c0.x * q0.x + c0.y * q0.y + c0.z * q0.z + c0.w * q0.w;
        dot += c1.x * q1.x + c1.y * q1.y + c1.z * q1.z + c1.w * q1.w;
        dot += c2.x * q2.x + c2.y * q2.y + c2.z * q2.z + c2.w * q2.w;
        dot += c3.x * q3.x + c3.y * q3.y + c3.z * q3.z + c3.w * q3.w;
#pragma unroll
        for (int off = 32; off; off >>= 1) dot += __shfl_xor(dot, off);
        if (lane == 0) {
            sims[sm] = dot / (qn[s] * cn);
            slab[sm] = lab;
        }
    }
}

// ---------------- top-5 + mean + round ----------------
__global__ void topk_kernel(const float* __restrict__ sims,
                            const float* __restrict__ slab,
                            float* __restrict__ out) {
    int gw = (int)((blockIdx.x * blockDim.x + threadIdx.x) >> 6);
    int lane = threadIdx.x & 63;
    if (gw >= SQ_) return;
    const float* srow = sims + (size_t)gw * MQ_;
    const float* lrow = slab + (size_t)gw * MQ_;
    float v[4];
#pragma unroll
    for (int i = 0; i < 4; ++i) v[i] = srow[lane + i * 64];
    float sum = 0.f;
    for (int t = 0; t < KQ_; ++t) {
        float bv = v[0];
        int bi = lane;
#pragma unroll
        for (int i = 1; i < 4; ++i) {
            if (v[i] > bv) { bv = v[i]; bi = lane + i * 64; }
        }
#pragma unroll
        for (int off = 32; off; off >>= 1) {
            float ov = __shfl_xor(bv, off);
            int oi = __shfl_xor(bi, off);
            if (ov > bv || (ov == bv && oi < bi)) { bv = ov; bi = oi; }
        }
        sum += lrow[bi];
        if ((bi & 63) == lane) v[bi >> 6] = -2.0f;   // sims in [-1,1]
    }
    if (lane == 0) out[gw] = rintf(sum / (float)KQ_);
}

extern "C" void kernel_launch(void* const* d_in, const int* in_sizes, int n_in,
                              void* d_out, int out_size, void* d_ws, size_t ws_size,
                              hipStream_t stream) {
    const float* q      = (const float*)d_in[0];   // [S, D]
    const float* bank   = (const float*)d_in[1];   // [N, D]
    const float* labels = (const float*)d_in[2];   // [N]
    const int*   bidx   = (const int*)d_in[3];     // [S, M]

    float* out = (float*)d_out;                    // [S]

    // workspace layout (all 4 B elements)
    float* sims     = (float*)d_ws;                // SM
    float* slab     = sims + SM_;                  // SM
    float* qn       = slab + SM_;                  // SQ
    int*   hist     = (int*)(qn + SQ_);            // NPAD
    int*   gstart   = hist + NPAD_;                // NPAD
    int*   cursor   = gstart + NPAD_;              // NPAD
    int*   blocksum = cursor + NPAD_;              // 128
    int*   blockoff = blocksum + 128;              // 128
    int*   ssm      = blockoff + 128;              // SM

    zero_kernel<<<(NPAD_ + 255) / 256, 256, 0, stream>>>(hist);
    hist_kernel<<<(SM_ + 255) / 256, 256, 0, stream>>>(bidx, hist);
    scanA_kernel<<<NBLK_, 1024, 0, stream>>>(hist, gstart, blocksum);
    scanB_kernel<<<1, 128, 0, stream>>>(blocksum, blockoff);
    scanC_kernel<<<(NPAD_ + 255) / 256, 256, 0, stream>>>(gstart, blockoff, cursor);
    scatter_kernel<<<(SM_ + 255) / 256, 256, 0, stream>>>(bidx, cursor, ssm);

    qnorm_kernel<<<SQ_ / 4, 256, 0, stream>>>(q, qn);

    // one wave per bank row: 100000 waves, 4 waves/block
    simg_kernel<<<(NROW_ + 3) / 4, 256, 0, stream>>>(q, bank, labels, hist, gstart, ssm,
                                                     qn, sims, slab);

    topk_kernel<<<SQ_ / 4, 256, 0, stream>>>(sims, slab, out);
}

// Round 5
// 85.150 us; speedup vs baseline: 2.0721x; 1.3320x over previous
//
#include <hip/hip_runtime.h>

#define SQ_ 512      // queries
#define MQ_ 256      // candidates per query
#define DQ_ 1024     // embedding dim
#define KQ_ 5
#define EPSQ 1e-8f

// One workgroup per query s: 16 waves x 16 candidates each.
// - q row loaded once per wave into registers; q-norm computed from those regs
//   (same accumulation order as the old qnorm_kernel -> identical value).
// - per-candidate bank-row load + dot/norm reduce is the exact R1 sequence
//   (same FMA order, same shuffle chain) -> bitwise-identical sims.
// - sims + candidate idx staged in LDS; wave 0 runs the R1 top-5 argmax loop,
//   gathers the 5 winning labels, writes round(mean) directly to out[s].
__global__ __launch_bounds__(1024) void fused_kernel(
    const float* __restrict__ q,
    const float* __restrict__ bank,
    const float* __restrict__ labels,
    const int* __restrict__ bidx,
    float* __restrict__ out) {
    __shared__ float s_sims[MQ_];
    __shared__ int   s_idx[MQ_];

    int s    = blockIdx.x;
    int tid  = threadIdx.x;
    int wave = tid >> 6;
    int lane = tid & 63;

    // stage this query's 256 candidate indices
    if (tid < MQ_) s_idx[tid] = bidx[(size_t)s * MQ_ + tid];
    __syncthreads();

    // q row -> registers (same layout as R1 sim kernel)
    const float4* qrow = (const float4*)(q + (size_t)s * DQ_);
    float4 q0 = qrow[lane];
    float4 q1 = qrow[lane + 64];
    float4 q2 = qrow[lane + 128];
    float4 q3 = qrow[lane + 192];

    // ||q||^2, same per-lane order as the old qnorm_kernel
    float qsq = q0.x * q0.x + q0.y * q0.y + q0.z * q0.z + q0.w * q0.w
              + q1.x * q1.x + q1.y * q1.y + q1.z * q1.z + q1.w * q1.w
              + q2.x * q2.x + q2.y * q2.y + q2.z * q2.z + q2.w * q2.w
              + q3.x * q3.x + q3.y * q3.y + q3.z * q3.z + q3.w * q3.w;
#pragma unroll
    for (int off = 32; off; off >>= 1) qsq += __shfl_xor(qsq, off);
    float qn = fmaxf(sqrtf(qsq), EPSQ);

    // 16 candidates per wave
    for (int t = 0; t < MQ_ / 16; ++t) {
        int m = wave * 16 + t;
        int idx = s_idx[m];
        const float4* crow = (const float4*)(bank + (size_t)idx * DQ_);
        float4 c0 = crow[lane];
        float4 c1 = crow[lane + 64];
        float4 c2 = crow[lane + 128];
        float4 c3 = crow[lane + 192];
        // exact R1 accumulation order
        float dot = 0.f, sq = 0.f;
        dot += c0.x * q0.x + c0.y * q0.y + c0.z * q0.z + c0.w * q0.w;
        sq  += c0.x * c0.x + c0.y * c0.y + c0.z * c0.z + c0.w * c0.w;
        dot += c1.x * q1.x + c1.y * q1.y + c1.z * q1.z + c1.w * q1.w;
        sq  += c1.x * c1.x + c1.y * c1.y + c1.z * c1.z + c1.w * c1.w;
        dot += c2.x * q2.x + c2.y * q2.y + c2.z * q2.z + c2.w * q2.w;
        sq  += c2.x * c2.x + c2.y * c2.y + c2.z * c2.z + c2.w * c2.w;
        dot += c3.x * q3.x + c3.y * q3.y + c3.z * q3.z + c3.w * q3.w;
        sq  += c3.x * c3.x + c3.y * c3.y + c3.z * c3.z + c3.w * c3.w;
#pragma unroll
        for (int off = 32; off; off >>= 1) {
            dot += __shfl_xor(dot, off);
            sq  += __shfl_xor(sq, off);
        }
        if (lane == 0) {
            float cn = fmaxf(sqrtf(sq), EPSQ);
            s_sims[m] = dot / (qn * cn);
        }
    }
    __syncthreads();

    // wave 0: top-5 + mean + round (exact R1 topk logic, sims from LDS)
    if (wave == 0) {
        float v[4];
#pragma unroll
        for (int i = 0; i < 4; ++i) v[i] = s_sims[lane + i * 64];
        float sum = 0.f;
        for (int t = 0; t < KQ_; ++t) {
            float bv = v[0];
            int bi = lane;
#pragma unroll
            for (int i = 1; i < 4; ++i) {
                if (v[i] > bv) { bv = v[i]; bi = lane + i * 64; }
            }
#pragma unroll
            for (int off = 32; off; off >>= 1) {
                float ov = __shfl_xor(bv, off);
                int oi = __shfl_xor(bi, off);
                if (ov > bv || (ov == bv && oi < bi)) { bv = ov; bi = oi; }
            }
            sum += labels[s_idx[bi]];
            if ((bi & 63) == lane) v[bi >> 6] = -2.0f;   // sims in [-1,1]
        }
        if (lane == 0) out[s] = rintf(sum / (float)KQ_);
    }
}

extern "C" void kernel_launch(void* const* d_in, const int* in_sizes, int n_in,
                              void* d_out, int out_size, void* d_ws, size_t ws_size,
                              hipStream_t stream) {
    const float* q      = (const float*)d_in[0];   // [S, D]
    const float* bank   = (const float*)d_in[1];   // [N, D]
    const float* labels = (const float*)d_in[2];   // [N]
    const int*   bidx   = (const int*)d_in[3];     // [S, M]
    float* out = (float*)d_out;                    // [S]

    fused_kernel<<<SQ_, 1024, 0, stream>>>(q, bank, labels, bidx, out);
}